// Round 2
// baseline (2999.141 us; speedup 1.0000x reference)
//
#include <hip/hip_runtime.h>

// multi_adaptive_hypergraph: out[n,h] = 1 iff softmax(relu(3*node@hyp^T))[n,h] > 0.5
// At most one softmax entry per row can exceed 0.5, and it is the argmax (always
// in top-K, K=32), so the top-K mask is a no-op for the thresholded output.
// Per row: m = max score, L = sum exp(s - m); emit 1 at argmax iff L < 2.

constexpr int D  = 1024;   // d_model
constexpr int H  = 1024;   // hyperedges per layer
constexpr int BM = 64;     // rows per block
constexpr int BN = 128;    // hyper cols per ht step
constexpr int BK = 32;     // k chunk
constexpr int NT = 256;    // threads per block

__global__ __launch_bounds__(NT)
void hyper_layer_kernel(const float* __restrict__ node,
                        const float* __restrict__ hyp,
                        float* __restrict__ out)
{
    // k-major LDS tiles so fragments are contiguous float4 (ds_read_b128).
    // +4 pad keeps 16B alignment of each k-row and breaks power-of-2 strides.
    __shared__ float As[BK][BM + 4];    // [32][68]
    __shared__ float Bs[BK][BN + 4];    // [32][132]

    const int tid  = threadIdx.x;
    const int tx   = tid & 15;          // 16 col-groups (8 cols each)
    const int ty   = tid >> 4;          // 16 row-groups (4 rows each)
    const int row0 = blockIdx.x * BM;

    // per-(thread,row) online softmax state
    float m_[4], l_[4];
    int   h_[4];
#pragma unroll
    for (int i = 0; i < 4; ++i) { m_[i] = -3.0e38f; l_[i] = 0.f; h_[i] = 0; }

    for (int ht = 0; ht < H / BN; ++ht) {
        float accm[4][8];
#pragma unroll
        for (int i = 0; i < 4; ++i)
#pragma unroll
            for (int j = 0; j < 8; ++j) accm[i][j] = 0.f;

        for (int kt = 0; kt < D / BK; ++kt) {
            // stage A: 64 rows x 32 k = 512 float4, 2 per thread
#pragma unroll
            for (int q = 0; q < 2; ++q) {
                int f  = tid + q * NT;     // 0..511
                int r  = f >> 3;           // 0..63
                int kg = f & 7;            // 0..7 (float4 group)
                float4 v = *reinterpret_cast<const float4*>(
                    &node[(size_t)(row0 + r) * D + (size_t)kt * BK + kg * 4]);
                As[kg * 4 + 0][r] = v.x;
                As[kg * 4 + 1][r] = v.y;
                As[kg * 4 + 2][r] = v.z;
                As[kg * 4 + 3][r] = v.w;
            }
            // stage B: 128 rows x 32 k = 1024 float4, 4 per thread
#pragma unroll
            for (int q = 0; q < 4; ++q) {
                int f  = tid + q * NT;     // 0..1023
                int r  = f >> 3;           // 0..127
                int kg = f & 7;
                float4 v = *reinterpret_cast<const float4*>(
                    &hyp[(size_t)(ht * BN + r) * D + (size_t)kt * BK + kg * 4]);
                Bs[kg * 4 + 0][r] = v.x;
                Bs[kg * 4 + 1][r] = v.y;
                Bs[kg * 4 + 2][r] = v.z;
                Bs[kg * 4 + 3][r] = v.w;
            }
            __syncthreads();

            // chunk accumulator (two-level accumulation: BLAS-class error so the
            // L<2 boundary decision matches the numpy reference)
            float accc[4][8];
#pragma unroll
            for (int i = 0; i < 4; ++i)
#pragma unroll
                for (int j = 0; j < 8; ++j) accc[i][j] = 0.f;

#pragma unroll
            for (int k = 0; k < BK; ++k) {
                float4 a  = *reinterpret_cast<const float4*>(&As[k][ty * 4]);
                float4 b0 = *reinterpret_cast<const float4*>(&Bs[k][tx * 8]);
                float4 b1 = *reinterpret_cast<const float4*>(&Bs[k][tx * 8 + 4]);
                float av[4] = {a.x, a.y, a.z, a.w};
                float bv[8] = {b0.x, b0.y, b0.z, b0.w, b1.x, b1.y, b1.z, b1.w};
#pragma unroll
                for (int i = 0; i < 4; ++i)
#pragma unroll
                    for (int j = 0; j < 8; ++j)
                        accc[i][j] = fmaf(av[i], bv[j], accc[i][j]);
            }
#pragma unroll
            for (int i = 0; i < 4; ++i)
#pragma unroll
                for (int j = 0; j < 8; ++j) accm[i][j] += accc[i][j];
            __syncthreads();
        }

        // epilogue for this hyper tile: online (max, sumexp, argmax) update
#pragma unroll
        for (int i = 0; i < 4; ++i) {
#pragma unroll
            for (int j = 0; j < 8; ++j) {
                float s = fmaxf(0.0f, 3.0f * accm[i][j]);
                int   h = ht * BN + tx * 8 + j;
                if (s > m_[i]) {
                    l_[i] = l_[i] * expf(m_[i] - s) + 1.0f;
                    m_[i] = s;
                    h_[i] = h;
                } else {
                    l_[i] += expf(s - m_[i]);
                }
            }
        }
    }

    // reduce (m,l,h) across the 16 tx lanes of each row (contiguous lanes in wave)
#pragma unroll
    for (int i = 0; i < 4; ++i) {
        float m = m_[i], l = l_[i];
        int   h = h_[i];
#pragma unroll
        for (int mask = 8; mask >= 1; mask >>= 1) {
            float om = __shfl_xor(m, mask);
            float ol = __shfl_xor(l, mask);
            int   oh = __shfl_xor(h, mask);
            float M  = fmaxf(m, om);
            l = l * expf(m - M) + ol * expf(om - M);
            h = (om > m) ? oh : h;
            m = M;
        }
        if (tx == 0 && l < 2.0f) {
            out[(size_t)(row0 + ty * 4 + i) * H + h] = 1.0f;
        }
    }
}

extern "C" void kernel_launch(void* const* d_in, const int* in_sizes, int n_in,
                              void* d_out, int out_size, void* d_ws, size_t ws_size,
                              hipStream_t stream)
{
    // Inputs arrive in setup_inputs() DICT order (interleaved):
    //   0: x (1,32768,1024)  [unused]
    //   1: hyp_emb_0 (1024,1024)   2: node_emb_0 (32768,1024)
    //   3: hyp_emb_1 (1024,1024)   4: node_emb_1 (8192,1024)
    //   5: hyp_emb_2 (1024,1024)   6: node_emb_2 (2048,1024)
    // Runtime check via in_sizes in case the harness ever uses signature order.
    const float* hyp[3];
    const float* node[3];
    if (in_sizes[2] == 32768 * 1024) {           // dict (interleaved) order
        hyp[0]  = (const float*)d_in[1];
        node[0] = (const float*)d_in[2];
        hyp[1]  = (const float*)d_in[3];
        node[1] = (const float*)d_in[4];
        hyp[2]  = (const float*)d_in[5];
        node[2] = (const float*)d_in[6];
    } else {                                     // signature order fallback
        hyp[0]  = (const float*)d_in[1];
        hyp[1]  = (const float*)d_in[2];
        hyp[2]  = (const float*)d_in[3];
        node[0] = (const float*)d_in[4];
        node[1] = (const float*)d_in[5];
        node[2] = (const float*)d_in[6];
    }
    float* out = (float*)d_out;

    const int N0 = 32768, N1 = 8192, N2 = 2048;

    // output is sparse ones over zeros: clear then scatter
    hipMemsetAsync(d_out, 0, (size_t)out_size * sizeof(float), stream);

    hyper_layer_kernel<<<N0 / BM, NT, 0, stream>>>(node[0], hyp[0], out);
    hyper_layer_kernel<<<N1 / BM, NT, 0, stream>>>(node[1], hyp[1],
                                                   out + (size_t)N0 * H);
    hyper_layer_kernel<<<N2 / BM, NT, 0, stream>>>(node[2], hyp[2],
                                                   out + (size_t)(N0 + N1) * H);
}

// Round 3
// 1509.892 us; speedup vs baseline: 1.9863x; 1.9863x over previous
//
#include <hip/hip_runtime.h>

// out[n,h] = 1 iff softmax(relu(3*node@hyp^T))[n,h] > 0.5.
// Only the row argmax can exceed 0.5 (and it's always in top-K), so:
//   emit 1 at argmax iff L = sum_h exp(s_h - m) < 2.
// Strategy: bf16 MFMA approximate scores (|err| <= 4 in dot units, bound:
// sum|a_i b_i| * 2^-8 <~ 3), collect per-row candidates within MARGIN=16 of the
// running max, then exact fp32 recheck of candidates only. Missing terms in L
// are < 1024*exp(-20) ~ 2e-6. Candidate-list overflow -> exact full-row path.

typedef __attribute__((ext_vector_type(8))) short short8;   // 8 bf16 = 4 VGPR
typedef __attribute__((ext_vector_type(4))) float f32x4;

constexpr int D  = 1024;
constexpr int H  = 1024;
constexpr int BM = 64;     // rows per block
constexpr int BN = 128;    // cols per ht tile
constexpr int BK = 32;     // k per stage step (= one 16x16x32 MFMA)
constexpr int NT = 256;    // 4 waves
constexpr int CAP = 32;    // candidate slots per row
constexpr float MARGIN = 16.0f;  // a-units: 20/3 exp window + 2*4 bf16 err

// order-preserving float<->uint encoding for atomicMax
__device__ inline unsigned enc_f(float f) {
    unsigned u = __float_as_uint(f);
    return (u & 0x80000000u) ? ~u : (u | 0x80000000u);
}
__device__ inline float dec_f(unsigned e) {
    unsigned u = (e & 0x80000000u) ? (e & 0x7FFFFFFFu) : ~e;
    return __uint_as_float(u);
}
// RNE float -> bf16 (inputs are finite)
__device__ inline unsigned short f2bf(float f) {
    unsigned u = __float_as_uint(f);
    u += 0x7FFFu + ((u >> 16) & 1u);
    return (unsigned short)(u >> 16);
}

__global__ __launch_bounds__(NT)
void fused_hyper_kernel(const float* __restrict__ node0, const float* __restrict__ hyp0,
                        const float* __restrict__ node1, const float* __restrict__ hyp1,
                        const float* __restrict__ node2, const float* __restrict__ hyp2,
                        float* __restrict__ out)
{
    // +8 bf16 pad -> 80B row stride: uniform bank spread for ds_read_b128,
    // 16B-aligned rows.
    __shared__ unsigned short As[BM][BK + 8];
    __shared__ unsigned short Bs[BN][BK + 8];
    __shared__ unsigned rowmax_e[BM];
    __shared__ int      cnt[BM];
    __shared__ unsigned short cand[BM][CAP];
    __shared__ int ovf_list[BM];
    __shared__ int ovf_n;
    __shared__ float rowcache[D];        // cold path only
    __shared__ unsigned red_max; __shared__ float red_l; __shared__ int red_h;

    const int bid = blockIdx.x;
    const float* node; const float* hyp; float* outp; int brow;
    if (bid < 512)      { node = node0; hyp = hyp0; outp = out;                          brow = bid; }
    else if (bid < 640) { node = node1; hyp = hyp1; outp = out + (size_t)32768 * 1024;   brow = bid - 512; }
    else                { node = node2; hyp = hyp2; outp = out + (size_t)40960 * 1024;   brow = bid - 640; }

    const int tid  = threadIdx.x;
    const int lane = tid & 63;
    const int wid  = tid >> 6;           // 0..3
    const int wr   = wid >> 1;           // wave row half (32 rows)
    const int wc   = wid & 1;            // wave col half (64 cols)
    const size_t row0 = (size_t)brow * BM;

    // zero this block's output rows (harness poisons d_out before every call)
    {
        float4 z = make_float4(0.f, 0.f, 0.f, 0.f);
        float4* o4 = reinterpret_cast<float4*>(outp + row0 * H);
        for (int q = 0; q < (BM * H / 4) / NT; ++q) o4[tid + q * NT] = z;
    }
    if (tid < BM) { rowmax_e[tid] = enc_f(-3.0e38f); cnt[tid] = 0; }
    if (tid == 0) ovf_n = 0;
    __syncthreads();

    for (int ht = 0; ht < H / BN; ++ht) {
        f32x4 acc[2][4];
#pragma unroll
        for (int m = 0; m < 2; ++m)
#pragma unroll
            for (int n = 0; n < 4; ++n) acc[m][n] = (f32x4)(0.f);

        for (int kt = 0; kt < D / BK; ++kt) {
            // stage A: 64x32 fp32 -> bf16, 2 float4/thread
#pragma unroll
            for (int q = 0; q < 2; ++q) {
                int f = tid + q * NT;
                int r = f >> 3, kg = f & 7;
                float4 v = *reinterpret_cast<const float4*>(
                    &node[(row0 + r) * D + kt * BK + kg * 4]);
                ushort4 b;
                b.x = f2bf(v.x); b.y = f2bf(v.y); b.z = f2bf(v.z); b.w = f2bf(v.w);
                *reinterpret_cast<ushort4*>(&As[r][kg * 4]) = b;
            }
            // stage B: 128x32 fp32 -> bf16, 4 float4/thread
#pragma unroll
            for (int q = 0; q < 4; ++q) {
                int f = tid + q * NT;
                int r = f >> 3, kg = f & 7;
                float4 v = *reinterpret_cast<const float4*>(
                    &hyp[(size_t)(ht * BN + r) * D + kt * BK + kg * 4]);
                ushort4 b;
                b.x = f2bf(v.x); b.y = f2bf(v.y); b.z = f2bf(v.z); b.w = f2bf(v.w);
                *reinterpret_cast<ushort4*>(&Bs[r][kg * 4]) = b;
            }
            __syncthreads();

            short8 af[2], bf[4];
#pragma unroll
            for (int m = 0; m < 2; ++m)
                af[m] = *reinterpret_cast<const short8*>(
                    &As[wr * 32 + m * 16 + (lane & 15)][(lane >> 4) * 8]);
#pragma unroll
            for (int n = 0; n < 4; ++n)
                bf[n] = *reinterpret_cast<const short8*>(
                    &Bs[wc * 64 + n * 16 + (lane & 15)][(lane >> 4) * 8]);
#pragma unroll
            for (int m = 0; m < 2; ++m)
#pragma unroll
                for (int n = 0; n < 4; ++n)
                    acc[m][n] = __builtin_amdgcn_mfma_f32_16x16x32_bf16(
                        af[m], bf[n], acc[m][n], 0, 0, 0);
            __syncthreads();
        }

        // ---- epilogue phase 1: fold this tile into per-row running max ----
#pragma unroll
        for (int m = 0; m < 2; ++m) {
#pragma unroll
            for (int j = 0; j < 4; ++j) {
                float vm = fmaxf(fmaxf(acc[m][0][j], acc[m][1][j]),
                                 fmaxf(acc[m][2][j], acc[m][3][j]));
#pragma unroll
                for (int s = 1; s < 16; s <<= 1) vm = fmaxf(vm, __shfl_xor(vm, s));
                if ((lane & 15) == 0) {
                    int rl = wr * 32 + m * 16 + (lane >> 4) * 4 + j;
                    atomicMax(&rowmax_e[rl], enc_f(vm));
                }
            }
        }
        __syncthreads();
        // ---- epilogue phase 2: collect candidates vs running max ----
#pragma unroll
        for (int m = 0; m < 2; ++m) {
#pragma unroll
            for (int j = 0; j < 4; ++j) {
                int rl = wr * 32 + m * 16 + (lane >> 4) * 4 + j;
                float thr = dec_f(rowmax_e[rl]) - MARGIN;
#pragma unroll
                for (int n = 0; n < 4; ++n) {
                    float v = acc[m][n][j];
                    if (v > thr) {
                        int slot = atomicAdd(&cnt[rl], 1);
                        if (slot < CAP)
                            cand[rl][slot] =
                                (unsigned short)(ht * BN + wc * 64 + n * 16 + (lane & 15));
                    }
                }
            }
        }
        // (no barrier needed: next ht's kt-loop barriers separate phases)
    }
    __syncthreads();

    // ---- exact recheck: one wave per row ----
    for (int r = wid; r < BM; r += 4) {
        int c = cnt[r];
        if (c > CAP) {
            if (lane == 0) { int p = atomicAdd(&ovf_n, 1); ovf_list[p] = r; }
            continue;
        }
        float m = -3.0e38f, l = 0.f; int hb = 0;
        const float* nr = &node[(row0 + r) * D];
        for (int i = 0; i < c; ++i) {
            int h = cand[r][i];
            const float* hr = &hyp[(size_t)h * D];
            float p = 0.f;
#pragma unroll
            for (int t = 0; t < 4; ++t) {
                float4 nv = *reinterpret_cast<const float4*>(&nr[lane * 16 + t * 4]);
                float4 hv = *reinterpret_cast<const float4*>(&hr[lane * 16 + t * 4]);
                p = fmaf(nv.x, hv.x, p); p = fmaf(nv.y, hv.y, p);
                p = fmaf(nv.z, hv.z, p); p = fmaf(nv.w, hv.w, p);
            }
#pragma unroll
            for (int s = 32; s >= 1; s >>= 1) p += __shfl_xor(p, s);
            float sc = fmaxf(0.f, 3.0f * p);
            if (sc > m) { l = l * expf(m - sc) + 1.0f; m = sc; hb = h; }
            else        { l += expf(sc - m); }
        }
        if (lane == 0 && l < 2.0f) outp[(row0 + r) * H + hb] = 1.0f;
    }
    __syncthreads();

    // ---- cold path: candidate overflow -> exact full row, block-wide ----
    for (int oi = 0; oi < ovf_n; ++oi) {
        int r = ovf_list[oi];
        for (int q = tid; q < D / 4; q += NT) {
            float4 v = *reinterpret_cast<const float4*>(&node[(row0 + r) * D + q * 4]);
            *reinterpret_cast<float4*>(&rowcache[q * 4]) = v;
        }
        if (tid == 0) { red_max = enc_f(-3.0e38f); red_l = 0.f; red_h = 1 << 30; }
        __syncthreads();
        float sc_loc[4];
#pragma unroll
        for (int u = 0; u < 4; ++u) {
            int h = tid * 4 + u;
            const float* hr = &hyp[(size_t)h * D];
            float p = 0.f;
            for (int t = 0; t < D; t += 4) {
                float4 hv = *reinterpret_cast<const float4*>(&hr[t]);
                p = fmaf(rowcache[t + 0], hv.x, p);
                p = fmaf(rowcache[t + 1], hv.y, p);
                p = fmaf(rowcache[t + 2], hv.z, p);
                p = fmaf(rowcache[t + 3], hv.w, p);
            }
            sc_loc[u] = fmaxf(0.f, 3.0f * p);
            atomicMax(&red_max, enc_f(sc_loc[u]));
        }
        __syncthreads();
        float m = dec_f(red_max);
        float lp = 0.f;
#pragma unroll
        for (int u = 0; u < 4; ++u) {
            lp += expf(sc_loc[u] - m);
            if (sc_loc[u] == m) atomicMin(&red_h, tid * 4 + u);
        }
        atomicAdd(&red_l, lp);
        __syncthreads();
        if (tid == 0 && red_l < 2.0f) outp[(row0 + r) * H + red_h] = 1.0f;
        __syncthreads();
    }
}

extern "C" void kernel_launch(void* const* d_in, const int* in_sizes, int n_in,
                              void* d_out, int out_size, void* d_ws, size_t ws_size,
                              hipStream_t stream)
{
    // setup_inputs() dict order (interleaved):
    //   0: x  1: hyp0  2: node0  3: hyp1  4: node1  5: hyp2  6: node2
    const float* hyp[3];
    const float* node[3];
    if (in_sizes[2] == 32768 * 1024) {           // dict (interleaved) order
        hyp[0]  = (const float*)d_in[1];
        node[0] = (const float*)d_in[2];
        hyp[1]  = (const float*)d_in[3];
        node[1] = (const float*)d_in[4];
        hyp[2]  = (const float*)d_in[5];
        node[2] = (const float*)d_in[6];
    } else {                                     // signature order fallback
        hyp[0]  = (const float*)d_in[1];
        hyp[1]  = (const float*)d_in[2];
        hyp[2]  = (const float*)d_in[3];
        node[0] = (const float*)d_in[4];
        node[1] = (const float*)d_in[5];
        node[2] = (const float*)d_in[6];
    }
    float* out = (float*)d_out;

    // blocks: layer0 512, layer1 128, layer2 32 (kernel zeroes its own rows)
    fused_hyper_kernel<<<672, NT, 0, stream>>>(node[0], hyp[0], node[1], hyp[1],
                                               node[2], hyp[2], out);
}

// Round 6
// 1173.915 us; speedup vs baseline: 2.5548x; 1.2862x over previous
//
#include <hip/hip_runtime.h>

// out[n,h] = 1 iff softmax(relu(3*node@hyp^T))[n,h] > 0.5.
// Only the row argmax can exceed 0.5 (always in top-K), so:
//   emit 1 at argmax iff L = sum_h exp(s_h - m) < 2.
// bf16 MFMA approx scores -> per-row candidates within MARGIN of running max
// -> exact fp32 recheck of candidates. Overflow rows -> exact full-row path.
//
// R6 == R4 design (R4/R5 benches were infra failures, not kernel failures):
// A panel (64 rows x 1024 k) resident in LDS as bf16 (staged once); B streamed
// in 64x128 bf16 chunks (pre-converted to d_ws) with register prefetch one
// step ahead. 1 block/CU (154 KB LDS) by design.

typedef __attribute__((ext_vector_type(8))) short short8;
typedef __attribute__((ext_vector_type(8))) unsigned short u16x8;
typedef __attribute__((ext_vector_type(4))) float f32x4;

constexpr int D  = 1024;
constexpr int H  = 1024;
constexpr int BM = 64;
constexpr int BN = 64;
constexpr int BK = 128;
constexpr int NT = 256;          // 4 waves, 2x2 wave grid
constexpr int CAP = 32;
constexpr float MARGIN = 16.0f;  // a-units: 20/3 exp window + 2*4 bf16 err
constexpr int LDA = D + 8;       // bf16 elems; 2064B row stride -> 4-bank skew
constexpr int LDB = BK + 8;      // 272B row stride -> 4-bank skew
constexpr int NBLK = 512 + 128 + 32;   // 672 = 8 * 84

static_assert((size_t)BM * LDA * 2 + (size_t)BN * LDB * 2 + BM * CAP * 2
              + BM * 4 * 3 + 64 < 160 * 1024, "LDS budget");

__device__ inline unsigned enc_f(float f) {
    unsigned u = __float_as_uint(f);
    return (u & 0x80000000u) ? ~u : (u | 0x80000000u);
}
__device__ inline float dec_f(unsigned e) {
    unsigned u = (e & 0x80000000u) ? (e & 0x7FFFFFFFu) : ~e;
    return __uint_as_float(u);
}
__device__ inline unsigned short f2bf(float f) {   // RNE, finite inputs
    unsigned u = __float_as_uint(f);
    u += 0x7FFFu + ((u >> 16) & 1u);
    return (unsigned short)(u >> 16);
}

// hyp fp32 -> bf16 into workspace (3 x 1M elems, exact multiple of grid)
__global__ void cvt_hyp_kernel(const float* __restrict__ h0,
                               const float* __restrict__ h1,
                               const float* __restrict__ h2,
                               unsigned short* __restrict__ o)
{
    size_t i8 = ((size_t)blockIdx.x * blockDim.x + threadIdx.x) * 8;
    const float* src = (i8 < (size_t)H * D) ? h0
                     : (i8 < 2ull * H * D ? h1 : h2);
    size_t rem = i8 & ((size_t)H * D - 1);
    float4 v0 = *(const float4*)&src[rem];
    float4 v1 = *(const float4*)&src[rem + 4];
    u16x8 b;
    b[0] = f2bf(v0.x); b[1] = f2bf(v0.y); b[2] = f2bf(v0.z); b[3] = f2bf(v0.w);
    b[4] = f2bf(v1.x); b[5] = f2bf(v1.y); b[6] = f2bf(v1.z); b[7] = f2bf(v1.w);
    *(u16x8*)&o[i8] = b;
}

template<int USE_BF>
__global__ __launch_bounds__(NT)
void fused_hyper_kernel(const float* __restrict__ node0, const float* __restrict__ hyp0,
                        const float* __restrict__ node1, const float* __restrict__ hyp1,
                        const float* __restrict__ node2, const float* __restrict__ hyp2,
                        const unsigned short* __restrict__ hypb_all,
                        float* __restrict__ out)
{
    __shared__ unsigned short As[BM * LDA];        // 132096 B
    __shared__ unsigned short Bs[BN * LDB];        // 17408 B (recheck: rowcache)
    __shared__ unsigned short cand[BM][CAP];       // 4096 B
    __shared__ unsigned rowmax_e[BM];
    __shared__ int cnt[BM];
    __shared__ int ovf_list[BM];
    __shared__ int ovf_n;
    __shared__ unsigned red_max; __shared__ float red_l; __shared__ int red_h;

    // XCD-contiguous work chunks: 672 = 8 * 84, bijective
    int bid = blockIdx.x;
    bid = (bid & 7) * (NBLK / 8) + (bid >> 3);

    const float* node; const float* hyp; float* outp; int brow, lyr;
    if (bid < 512)      { node = node0; hyp = hyp0; outp = out;                        brow = bid;       lyr = 0; }
    else if (bid < 640) { node = node1; hyp = hyp1; outp = out + (size_t)32768 * H;    brow = bid - 512; lyr = 1; }
    else                { node = node2; hyp = hyp2; outp = out + (size_t)40960 * H;    brow = bid - 640; lyr = 2; }
    const unsigned short* hypb =
        USE_BF ? hypb_all + (size_t)lyr * H * D : (const unsigned short*)nullptr;

    const int tid  = threadIdx.x;
    const int lane = tid & 63;
    const int wid  = tid >> 6;
    const int wr   = wid >> 1, wc = wid & 1;
    const int l15  = lane & 15, l4 = lane >> 4;
    const size_t row0 = (size_t)brow * BM;

    // zero this block's output rows (d_out is poisoned before every call)
    {
        float4 z = make_float4(0.f, 0.f, 0.f, 0.f);
        float4* o4 = reinterpret_cast<float4*>(outp + row0 * H);
#pragma unroll 8
        for (int q = 0; q < (BM * H / 4) / NT; ++q) o4[tid + q * NT] = z;
    }
    if (tid < BM) { rowmax_e[tid] = enc_f(-3.0e38f); cnt[tid] = 0; }
    if (tid == 0) ovf_n = 0;

    // ---- stage full A panel once: 64 rows x 1024 k, fp32 -> bf16 ----
#pragma unroll 8
    for (int r = 0; r < BM; ++r) {
        float4 v = *(const float4*)&node[(row0 + r) * (size_t)D + tid * 4];
        ushort4 b;
        b.x = f2bf(v.x); b.y = f2bf(v.y); b.z = f2bf(v.z); b.w = f2bf(v.w);
        *(ushort4*)&As[r * LDA + tid * 4] = b;
    }
    // (first barrier of the s-loop publishes As + shared inits)

    float4 pf[8];
    u16x8  pfb[4];
    auto issue_pf = [&](int nt_, int s_) {
        if constexpr (USE_BF) {
            const unsigned short* base = hypb + (size_t)(nt_ * BN) * D + s_ * BK;
#pragma unroll
            for (int q = 0; q < 4; ++q) {
                int c = (tid >> 4) + 16 * q;
                pfb[q] = *(const u16x8*)&base[(size_t)c * D + (tid & 15) * 8];
            }
        } else {
            const float* base = hyp + (size_t)(nt_ * BN) * D + s_ * BK;
#pragma unroll
            for (int q = 0; q < 8; ++q) {
                int c = (tid >> 5) + 8 * q;
                pf[q] = *(const float4*)&base[(size_t)c * D + (tid & 31) * 4];
            }
        }
    };
    auto commit_pf = [&]() {
        if constexpr (USE_BF) {
#pragma unroll
            for (int q = 0; q < 4; ++q) {
                int c = (tid >> 4) + 16 * q;
                *(u16x8*)&Bs[c * LDB + (tid & 15) * 8] = pfb[q];
            }
        } else {
#pragma unroll
            for (int q = 0; q < 8; ++q) {
                int c = (tid >> 5) + 8 * q;
                ushort4 b;
                b.x = f2bf(pf[q].x); b.y = f2bf(pf[q].y);
                b.z = f2bf(pf[q].z); b.w = f2bf(pf[q].w);
                *(ushort4*)&Bs[c * LDB + (tid & 31) * 4] = b;
            }
        }
    };

    issue_pf(0, 0);
    for (int nt = 0; nt < H / BN; ++nt) {
        f32x4 acc[2][2];
#pragma unroll
        for (int m = 0; m < 2; ++m)
#pragma unroll
            for (int n = 0; n < 2; ++n) acc[m][n] = (f32x4)(0.f);

        for (int s = 0; s < D / BK; ++s) {
            __syncthreads();                         // Bs free / As+inits published
            commit_pf();
            if (s + 1 < D / BK)       issue_pf(nt, s + 1);
            else if (nt + 1 < H / BN) issue_pf(nt + 1, 0);  // overlaps epilogue
            __syncthreads();                         // Bs ready
#pragma unroll
            for (int ks = 0; ks < BK / 32; ++ks) {
                const int ko = s * BK + ks * 32 + l4 * 8;
                const int kb = ks * 32 + l4 * 8;
                short8 a0 = *(const short8*)&As[(wr * 32 + l15) * LDA + ko];
                short8 a1 = *(const short8*)&As[(wr * 32 + 16 + l15) * LDA + ko];
                short8 b0 = *(const short8*)&Bs[(wc * 32 + l15) * LDB + kb];
                short8 b1 = *(const short8*)&Bs[(wc * 32 + 16 + l15) * LDB + kb];
                acc[0][0] = __builtin_amdgcn_mfma_f32_16x16x32_bf16(a0, b0, acc[0][0], 0, 0, 0);
                acc[0][1] = __builtin_amdgcn_mfma_f32_16x16x32_bf16(a0, b1, acc[0][1], 0, 0, 0);
                acc[1][0] = __builtin_amdgcn_mfma_f32_16x16x32_bf16(a1, b0, acc[1][0], 0, 0, 0);
                acc[1][1] = __builtin_amdgcn_mfma_f32_16x16x32_bf16(a1, b1, acc[1][1], 0, 0, 0);
            }
        }

        // ---- epilogue phase 1: fold tile max into per-row running max ----
#pragma unroll
        for (int m = 0; m < 2; ++m) {
#pragma unroll
            for (int j = 0; j < 4; ++j) {
                float vm = fmaxf(acc[m][0][j], acc[m][1][j]);
#pragma unroll
                for (int sh = 1; sh < 16; sh <<= 1) vm = fmaxf(vm, __shfl_xor(vm, sh));
                if (l15 == 0)
                    atomicMax(&rowmax_e[wr * 32 + m * 16 + l4 * 4 + j], enc_f(vm));
            }
        }
        __syncthreads();
        // ---- epilogue phase 2: collect candidates vs running max ----
#pragma unroll
        for (int m = 0; m < 2; ++m) {
#pragma unroll
            for (int j = 0; j < 4; ++j) {
                int rl = wr * 32 + m * 16 + l4 * 4 + j;
                float thr = dec_f(rowmax_e[rl]) - MARGIN;
#pragma unroll
                for (int n = 0; n < 2; ++n) {
                    if (acc[m][n][j] > thr) {
                        int slot = atomicAdd(&cnt[rl], 1);
                        if (slot < CAP)
                            cand[rl][slot] =
                                (unsigned short)(nt * BN + wc * 32 + n * 16 + l15);
                    }
                }
            }
        }
        // next nt's first barrier separates phase2 from Bs overwrite / phase1
    }
    __syncthreads();

    // ---- exact fp32 recheck: 16-lane groups, 4 rows per wave in flight ----
    {
        const int sub = l4;        // group id 0..3
        const int sl  = l15;       // lane in group
        for (int rb = 0; rb < 4; ++rb) {
            int r = rb * 16 + wid * 4 + sub;
            int c = cnt[r];
            if (c > CAP) {
                if (sl == 0) { int p = atomicAdd(&ovf_n, 1); ovf_list[p] = r; }
                continue;
            }
            float4 nv[16];
#pragma unroll
            for (int t = 0; t < 16; ++t)
                nv[t] = *(const float4*)&node[(row0 + r) * (size_t)D + t * 64 + sl * 4];
            float m = -3.0e38f, l = 0.f; int hb = 0;
            for (int i = 0; i < c; ++i) {
                int h = cand[r][i];
                const float* hr = &hyp[(size_t)h * D];
                float p = 0.f;
#pragma unroll
                for (int t = 0; t < 16; ++t) {
                    float4 hv = *(const float4*)&hr[t * 64 + sl * 4];
                    p = fmaf(nv[t].x, hv.x, p); p = fmaf(nv[t].y, hv.y, p);
                    p = fmaf(nv[t].z, hv.z, p); p = fmaf(nv[t].w, hv.w, p);
                }
#pragma unroll
                for (int sh = 8; sh >= 1; sh >>= 1) p += __shfl_xor(p, sh);
                float sc = fmaxf(0.f, 3.0f * p);
                if (sc > m) { l = l * expf(m - sc) + 1.0f; m = sc; hb = h; }
                else        { l += expf(sc - m); }
            }
            if (sl == 0 && c > 0 && l < 2.0f)
                outp[(row0 + r) * (size_t)H + hb] = 1.0f;
        }
    }
    __syncthreads();

    // ---- cold path: candidate overflow -> exact full row, block-wide ----
    float* rowcache = reinterpret_cast<float*>(Bs);   // Bs dead; 4KB of 17KB
    for (int oi = 0; oi < ovf_n; ++oi) {
        int r = ovf_list[oi];
        for (int q = tid; q < D / 4; q += NT)
            *(float4*)&rowcache[q * 4] =
                *(const float4*)&node[(row0 + r) * (size_t)D + q * 4];
        if (tid == 0) { red_max = enc_f(-3.0e38f); red_l = 0.f; red_h = 1 << 30; }
        __syncthreads();
        float sc_loc[4];
#pragma unroll
        for (int u = 0; u < 4; ++u) {
            const float* hr = &hyp[(size_t)(tid * 4 + u) * D];
            float p = 0.f;
            for (int t = 0; t < D; t += 4) {
                float4 hv = *(const float4*)&hr[t];
                p = fmaf(rowcache[t + 0], hv.x, p);
                p = fmaf(rowcache[t + 1], hv.y, p);
                p = fmaf(rowcache[t + 2], hv.z, p);
                p = fmaf(rowcache[t + 3], hv.w, p);
            }
            sc_loc[u] = fmaxf(0.f, 3.0f * p);
            atomicMax(&red_max, enc_f(sc_loc[u]));
        }
        __syncthreads();
        float mm = dec_f(red_max);
        float lp = 0.f;
#pragma unroll
        for (int u = 0; u < 4; ++u) {
            lp += expf(sc_loc[u] - mm);
            if (sc_loc[u] == mm) atomicMin(&red_h, tid * 4 + u);
        }
        atomicAdd(&red_l, lp);
        __syncthreads();
        if (tid == 0 && red_l < 2.0f) outp[(row0 + r) * (size_t)H + red_h] = 1.0f;
        __syncthreads();
    }
}

extern "C" void kernel_launch(void* const* d_in, const int* in_sizes, int n_in,
                              void* d_out, int out_size, void* d_ws, size_t ws_size,
                              hipStream_t stream)
{
    // setup_inputs() dict order (interleaved):
    //   0: x  1: hyp0  2: node0  3: hyp1  4: node1  5: hyp2  6: node2
    const float* hyp[3];
    const float* node[3];
    if (in_sizes[2] == 32768 * 1024) {           // dict (interleaved) order
        hyp[0]  = (const float*)d_in[1];
        node[0] = (const float*)d_in[2];
        hyp[1]  = (const float*)d_in[3];
        node[1] = (const float*)d_in[4];
        hyp[2]  = (const float*)d_in[5];
        node[2] = (const float*)d_in[6];
    } else {                                     // signature order fallback
        hyp[0]  = (const float*)d_in[1];
        hyp[1]  = (const float*)d_in[2];
        hyp[2]  = (const float*)d_in[3];
        node[0] = (const float*)d_in[4];
        node[1] = (const float*)d_in[5];
        node[2] = (const float*)d_in[6];
    }
    float* out = (float*)d_out;

    const size_t bfbytes = (size_t)3 * H * D * sizeof(unsigned short);  // 6 MB
    if (ws_size >= bfbytes) {
        unsigned short* hb = (unsigned short*)d_ws;
        cvt_hyp_kernel<<<(3 * H * D / 8) / 256, 256, 0, stream>>>(
            hyp[0], hyp[1], hyp[2], hb);
        fused_hyper_kernel<1><<<NBLK, NT, 0, stream>>>(
            node[0], hyp[0], node[1], hyp[1], node[2], hyp[2], hb, out);
    } else {
        fused_hyper_kernel<0><<<NBLK, NT, 0, stream>>>(
            node[0], hyp[0], node[1], hyp[1], node[2], hyp[2], nullptr, out);
    }
}